// Round 4
// baseline (270.491 us; speedup 1.0000x reference)
//
#include <hip/hip_runtime.h>
#include <stdint.h>
#include <type_traits>

#define NH 16
#define NKV 4
#define HD 128
#define QS (NH*HD)     /* 2048 */
#define KSR (NKV*HD)   /* 512  */
#define SCALE 0.08838834764831845f
#define LOG2E 1.4426950408889634f
#define CT 32          /* tiles per chunk (split mode) */

typedef float f32x4 __attribute__((ext_vector_type(4)));
typedef __bf16 bf16x8 __attribute__((ext_vector_type(8)));
typedef __bf16 bf16x4 __attribute__((ext_vector_type(4)));

__device__ __forceinline__ void gll16(const void* g, void* l) {
  __builtin_amdgcn_global_load_lds((const __attribute__((address_space(1))) void*)g,
                                   (__attribute__((address_space(3))) void*)l, 16, 0, 0);
}

// ---------------------------------------------------------------------------
// Prepass: K -> bf16 * (SCALE*log2e), swizzled image [tile][row][col^swz];
//          V -> bf16 transposed image [tile][d][key^swz].
// All global writes coalesced; V transpose via gather reads (32B sectors).
// ---------------------------------------------------------------------------
__global__ __launch_bounds__(256) void prepass_kernel(
    const float* __restrict__ k, const float* __restrict__ v,
    __bf16* __restrict__ kb, __bf16* __restrict__ vb) {
  const int tid = threadIdx.x;
  const int kvh = blockIdx.x >> 6;
  const int kt = blockIdx.x & 63;
  const size_t ibase = (size_t)(kvh * 64 + kt) << 13;
  const float KS = SCALE * LOG2E;
  // K: rows coalesced both sides
#pragma unroll
  for (int rep = 0; rep < 4; ++rep) {
    int i = tid + rep * 256;
    int row = i >> 4, c8 = (i & 15) << 3;
    const float* src = k + (size_t)(kt * 64 + row) * KSR + kvh * HD + c8;
    f32x4 a = *(const f32x4*)src, b = *(const f32x4*)(src + 4);
    bf16x8 t;
#pragma unroll
    for (int e = 0; e < 4; ++e) { t[e] = (__bf16)(a[e] * KS); t[4 + e] = (__bf16)(b[e] * KS); }
    *(bf16x8*)&kb[ibase + row * 128 + (c8 ^ ((row & 7) << 3))] = t;
  }
  // V: gather-transpose, coalesced 16B image writes
#pragma unroll
  for (int rep = 0; rep < 4; ++rep) {
    int i = tid + rep * 256;
    int d = i >> 3, k8 = (i & 7) << 3;
    bf16x8 t;
#pragma unroll
    for (int w = 0; w < 8; ++w)
      t[w] = (__bf16)v[(size_t)(kt * 64 + k8 + w) * KSR + kvh * HD + d];
    *(bf16x8*)&vb[ibase + d * 64 + (k8 ^ ((d & 7) << 3))] = t;
  }
}

// ---------------------------------------------------------------------------
// Attention. 4 waves x 32 q-rows; KVBLK=64; K/V via global_load_lds from
// prepass images (dbuf, counted vmcnt, raw barriers). Deferred-PV pipeline:
// iter j runs QK(j) then softmax(j) interleaved with PV(j-1); rescale after.
// ---------------------------------------------------------------------------
__global__ __launch_bounds__(256, 2) void attn_kernel(
    const float* __restrict__ q, const __bf16* __restrict__ kb,
    const __bf16* __restrict__ vb, float* __restrict__ o,
    __bf16* __restrict__ opart, float2* __restrict__ stats, int mode) {
  __shared__ __bf16 Kt[2][64][128];
  __shared__ __bf16 VT[2][128][64];
  __shared__ __bf16 Pt[4][32][64];

  const int tid = threadIdx.x;
  const int lane = tid & 63;
  const int wid = tid >> 6;
  const int g = lane >> 4, r = lane & 15;
  const int h = blockIdx.x & 15;
  const int u = blockIdx.x >> 4;

  int qt, c;
  if (mode) { qt = 31 - u; c = 0; }
  else if (u < 16) { qt = 31 - u; c = 0; }
  else { qt = 47 - u; c = (u < 32) ? 1 : 0; }

  const int kvh = h >> 2;
  const int nch = (!mode && qt >= 16) ? 2 : 1;
  const int t0 = c * CT;
  const int maxt = mode ? 64 : CT;
  int ntb = 2 * qt + 2 - t0;
  if (ntb > maxt) ntb = maxt;
  const int qrow0 = qt * 128 + wid * 32;
  const int limit32 = qt * 4 + wid + 1;

  // ---- Q fragments ----
  bf16x8 qf[2][4];
#pragma unroll
  for (int qh = 0; qh < 2; ++qh)
#pragma unroll
    for (int ks = 0; ks < 4; ++ks) {
      const float* src = q + (size_t)(qrow0 + qh * 16 + r) * QS + h * HD + 32 * ks + 8 * g;
      f32x4 a = *(const f32x4*)src, b = *(const f32x4*)(src + 4);
      bf16x8 tt;
#pragma unroll
      for (int e = 0; e < 4; ++e) { tt[e] = (__bf16)a[e]; tt[4 + e] = (__bf16)b[e]; }
      qf[qh][ks] = tt;
    }

  f32x4 oacc[2][8];
#pragma unroll
  for (int qh = 0; qh < 2; ++qh)
#pragma unroll
    for (int nt = 0; nt < 8; ++nt) oacc[qh][nt] = (f32x4){0.f, 0.f, 0.f, 0.f};
  float mrun[2] = {-1e30f, -1e30f}, lrun[2] = {0.f, 0.f};

  f32x4 sacc[2][4];
  bf16x8 pa[2][2];
  float cfv[2];
  bool dor[2] = {false, false};

  auto stageK = [&](int ktg, int buf) {
    const __bf16* gK = kb + (((size_t)(kvh * 64 + ktg)) << 13) + tid * 8;
    __bf16* lK = &Kt[buf][0][0] + tid * 8;
#pragma unroll
    for (int i = 0; i < 4; ++i) gll16(gK + i * 2048, lK + i * 2048);
  };
  auto stageV = [&](int ktg, int buf) {
    const __bf16* gV = vb + (((size_t)(kvh * 64 + ktg)) << 13) + tid * 8;
    __bf16* lV = &VT[buf][0][0] + tid * 8;
#pragma unroll
    for (int i = 0; i < 4; ++i) gll16(gV + i * 2048, lV + i * 2048);
  };

  auto pa_load = [&]() {
#pragma unroll
    for (int qh = 0; qh < 2; ++qh)
#pragma unroll
      for (int kc = 0; kc < 2; ++kc)
        pa[qh][kc] = *(const bf16x8*)&Pt[wid][qh * 16 + r][(32 * kc + 8 * g) ^ ((r & 7) << 3)];
  };

  auto qk = [&](auto NGC, int buf) {
    constexpr int NG = decltype(NGC)::value;
#pragma unroll
    for (int nt2 = 0; nt2 < NG; ++nt2) {
      bf16x8 kf[4];
#pragma unroll
      for (int ks = 0; ks < 4; ++ks)
        kf[ks] = *(const bf16x8*)&Kt[buf][16 * nt2 + r][(32 * ks + 8 * g) ^ ((r & 7) << 3)];
      __builtin_amdgcn_s_setprio(1);
#pragma unroll
      for (int qh = 0; qh < 2; ++qh) {
        f32x4 cacc = (f32x4){0.f, 0.f, 0.f, 0.f};
#pragma unroll
        for (int ks = 0; ks < 4; ++ks)
          cacc = __builtin_amdgcn_mfma_f32_16x16x32_bf16(kf[ks], qf[qh][ks], cacc, 0, 0, 0);
        sacc[qh][nt2] = cacc;  // S^T (pre-scaled to log2 units)
      }
      __builtin_amdgcn_s_setprio(0);
    }
  };

  auto softmax_f = [&](auto NGC) {
    constexpr int NG = decltype(NGC)::value;
#pragma unroll
    for (int qh = 0; qh < 2; ++qh) {
      float mx = sacc[qh][0][0];
#pragma unroll
      for (int nt2 = 0; nt2 < NG; ++nt2)
#pragma unroll
        for (int j = 0; j < 4; ++j)
          if (nt2 || j) mx = fmaxf(mx, sacc[qh][nt2][j]);
      mx = fmaxf(mx, __shfl_xor(mx, 16));
      mx = fmaxf(mx, __shfl_xor(mx, 32));
      float mold = mrun[qh];
      float mnew = fmaxf(mold, mx);
      unsigned long long chg = __ballot(mx > mold);
      mrun[qh] = mnew;
      float ts = 0.f;
#pragma unroll
      for (int nt2 = 0; nt2 < 4; ++nt2) {
        bf16x4 pw;
        if (nt2 < NG) {
#pragma unroll
          for (int j = 0; j < 4; ++j) {
            float p = exp2f(sacc[qh][nt2][j] - mnew);
            ts += p;
            pw[j] = (__bf16)p;
          }
        } else {
#pragma unroll
          for (int j = 0; j < 4; ++j) pw[j] = (__bf16)0.f;
        }
        *(bf16x4*)&Pt[wid][qh * 16 + r][(16 * nt2 + 4 * g) ^ ((r & 7) << 3)] = pw;
      }
      ts += __shfl_xor(ts, 16);
      ts += __shfl_xor(ts, 32);
      if (chg) {
        float cf = exp2f(mold - mnew);
        lrun[qh] = lrun[qh] * cf + ts;
        cfv[qh] = cf;
        dor[qh] = true;
      } else {
        lrun[qh] += ts;
        dor[qh] = false;
      }
    }
  };

  auto zero_fill = [&]() {
    bf16x4 pw;
#pragma unroll
    for (int j = 0; j < 4; ++j) pw[j] = (__bf16)0.f;
#pragma unroll
    for (int qh = 0; qh < 2; ++qh)
#pragma unroll
      for (int nt2 = 0; nt2 < 4; ++nt2)
        *(bf16x4*)&Pt[wid][qh * 16 + r][(16 * nt2 + 4 * g) ^ ((r & 7) << 3)] = pw;
    dor[0] = dor[1] = false;
  };

  auto pv_f = [&](int vbuf) {
    __builtin_amdgcn_s_setprio(1);
#pragma unroll
    for (int nt = 0; nt < 8; ++nt)
#pragma unroll
      for (int kc = 0; kc < 2; ++kc) {
        bf16x8 vf = *(const bf16x8*)&VT[vbuf][16 * nt + r][(32 * kc + 8 * g) ^ ((r & 7) << 3)];
#pragma unroll
        for (int qh = 0; qh < 2; ++qh)
          oacc[qh][nt] = __builtin_amdgcn_mfma_f32_16x16x32_bf16(pa[qh][kc], vf, oacc[qh][nt], 0, 0, 0);
      }
    __builtin_amdgcn_s_setprio(0);
  };

  auto rescale_f = [&]() {
#pragma unroll
    for (int qh = 0; qh < 2; ++qh)
      if (dor[qh]) {
#pragma unroll
        for (int j = 0; j < 4; ++j) {
          float cfj = __shfl(cfv[qh], 20 * g + j);
#pragma unroll
          for (int nt = 0; nt < 8; ++nt) oacc[qh][nt][j] *= cfj;
        }
      }
  };

  constexpr auto IC4 = std::integral_constant<int, 4>{};
  constexpr auto IC2 = std::integral_constant<int, 2>{};

  // ---- prologue: K(0) ----
  stageK(t0, 0);

  // ---- iter 0 (no PV yet) ----
  {
    if (1 < ntb) stageK(t0 + 1, 1);
    stageV(t0, 0);
    if (1 < ntb) asm volatile("s_waitcnt vmcnt(8)" ::: "memory");
    else         asm volatile("s_waitcnt vmcnt(4)" ::: "memory");
    __builtin_amdgcn_s_barrier();
    const int rem = limit32 - 2 * t0;
    if (rem >= 2)      { qk(IC4, 0); softmax_f(IC4); }
    else if (rem == 1) { qk(IC2, 0); softmax_f(IC2); }
    else               zero_fill();
    __builtin_amdgcn_s_barrier();
  }

  // ---- main loop ----
  for (int j = 1; j < ntb; ++j) {
    const int buf = j & 1;
    if (j + 1 < ntb) {
      stageK(t0 + j + 1, buf ^ 1);
      stageV(t0 + j, buf);
      asm volatile("s_waitcnt vmcnt(8)" ::: "memory");
    } else {
      stageV(t0 + j, buf);
      asm volatile("s_waitcnt vmcnt(4)" ::: "memory");
    }
    __builtin_amdgcn_s_barrier();
    pa_load();  // P(j-1) before Pt is overwritten
    const int rem = limit32 - 2 * (t0 + j);
    if (rem >= 2) {
      qk(IC4, buf);
      softmax_f(IC4);   // softmax VALU interleaves with PV MFMAs below
      pv_f(buf ^ 1);
      rescale_f();
    } else if (rem == 1) {
      qk(IC2, buf);
      softmax_f(IC2);
      pv_f(buf ^ 1);
      rescale_f();
    } else {
      zero_fill();
      pv_f(buf ^ 1);
    }
    __builtin_amdgcn_s_barrier();
  }

  // ---- epilogue: final PV ----
  asm volatile("s_waitcnt vmcnt(0)" ::: "memory");
  __builtin_amdgcn_s_barrier();
  pa_load();
  pv_f((ntb - 1) & 1);

  if (nch == 1) {
#pragma unroll
    for (int qh = 0; qh < 2; ++qh) {
      float invl = 1.0f / lrun[qh];
#pragma unroll
      for (int j = 0; j < 4; ++j) {
        float iv = __shfl(invl, 20 * g + j);
        int row = qrow0 + qh * 16 + 4 * g + j;
#pragma unroll
        for (int nt = 0; nt < 8; ++nt)
          o[(size_t)row * QS + h * HD + 16 * nt + r] = oacc[qh][nt][j] * iv;
      }
    }
  } else {
    const int slot = (h * 16 + (qt - 16)) * 2 + c;
    __bf16* op = opart + (size_t)slot * 16384;
#pragma unroll
    for (int qh = 0; qh < 2; ++qh) {
#pragma unroll
      for (int j = 0; j < 4; ++j) {
        int rl = wid * 32 + qh * 16 + 4 * g + j;
#pragma unroll
        for (int nt = 0; nt < 8; ++nt)
          op[rl * 128 + 16 * nt + r] = (__bf16)oacc[qh][nt][j];
      }
      if (g == 0)
        stats[slot * 128 + wid * 32 + qh * 16 + r] = make_float2(mrun[qh], lrun[qh]);
    }
  }
}

// ---------------------------------------------------------------------------
// Merge two chunk-partials per row (qt >= 16 only); stats are log2-domain.
// ---------------------------------------------------------------------------
__global__ __launch_bounds__(256) void merge_kernel(
    const __bf16* __restrict__ opart, const float2* __restrict__ stats,
    float* __restrict__ o) {
  const int bi = blockIdx.x;
  const int qtr = bi >> 7;
  const int rm = bi & 127;
  const int h = rm >> 3;
  const int rb = rm & 7;
  const int t = threadIdx.x;
  const int rl = rb * 16 + (t >> 4);
  const int d8 = (t & 15) << 3;
  const int slot = (h * 16 + qtr) * 2;
  float2 s0 = stats[slot * 128 + rl];
  float2 s1 = stats[(slot + 1) * 128 + rl];
  float M = fmaxf(s0.x, s1.x);
  float w0 = exp2f(s0.x - M), w1 = exp2f(s1.x - M);
  float inv = 1.0f / (s0.y * w0 + s1.y * w1);
  bf16x8 a = *(const bf16x8*)&opart[(size_t)slot * 16384 + rl * 128 + d8];
  bf16x8 b = *(const bf16x8*)&opart[(size_t)(slot + 1) * 16384 + rl * 128 + d8];
  float* dst = o + (size_t)((16 + qtr) * 128 + rl) * QS + h * HD + d8;
  f32x4 o0, o1;
#pragma unroll
  for (int e = 0; e < 4; ++e) o0[e] = ((float)a[e] * w0 + (float)b[e] * w1) * inv;
#pragma unroll
  for (int e = 0; e < 4; ++e) o1[e] = ((float)a[4 + e] * w0 + (float)b[4 + e] * w1) * inv;
  *(f32x4*)dst = o0;
  *(f32x4*)(dst + 4) = o1;
}

// ---------------------------------------------------------------------------
// Cache copy then scatter
// ---------------------------------------------------------------------------
__global__ void copy_caches_kernel(const f32x4* __restrict__ kc, const f32x4* __restrict__ vc,
                                   f32x4* __restrict__ okc, f32x4* __restrict__ ovc, int n4) {
  int i = blockIdx.x * blockDim.x + threadIdx.x;
  int stride = gridDim.x * blockDim.x;
  for (; i < n4; i += stride) {
    okc[i] = kc[i];
    ovc[i] = vc[i];
  }
}

__global__ void scatter_kernel(const float* __restrict__ k, const float* __restrict__ v,
                               const int* __restrict__ slot, float* __restrict__ okc,
                               float* __restrict__ ovc, int t) {
  int i = blockIdx.x * blockDim.x + threadIdx.x;
  int row = i >> 7, c = i & 127;
  if (row < t) {
    int s = slot[row];
    ((f32x4*)okc)[(size_t)s * 128 + c] = ((const f32x4*)k)[(size_t)row * 128 + c];
    ((f32x4*)ovc)[(size_t)s * 128 + c] = ((const f32x4*)v)[(size_t)row * 128 + c];
  }
}

extern "C" void kernel_launch(void* const* d_in, const int* in_sizes, int n_in,
                              void* d_out, int out_size, void* d_ws, size_t ws_size,
                              hipStream_t stream) {
  const float* q = (const float*)d_in[0];
  const float* k = (const float*)d_in[1];
  const float* v = (const float*)d_in[2];
  const float* kc = (const float*)d_in[3];
  const float* vc = (const float*)d_in[4];
  const int* slot = (const int*)d_in[5];

  const int t = in_sizes[0] / QS;        // 4096
  const int nslots = in_sizes[3] / KSR;  // 8192

  float* o = (float*)d_out;
  float* okc = o + (size_t)t * QS;
  float* ovc = okc + (size_t)nslots * KSR;

  __bf16* kb = (__bf16*)d_ws;
  __bf16* vb = kb + 2097152;
  const size_t off_op = (size_t)8 << 20;
  const size_t off_st = off_op + (size_t)512 * 16384 * 2;
  const size_t need_split = off_st + (size_t)512 * 128 * 8;
  __bf16* opart = (__bf16*)((char*)d_ws + off_op);
  float2* stats = (float2*)((char*)d_ws + off_st);

  const int mode = (ws_size >= need_split) ? 0 : 1;

  hipLaunchKernelGGL(prepass_kernel, dim3(256), dim3(256), 0, stream, k, v, kb, vb);
  hipLaunchKernelGGL(attn_kernel, dim3((mode ? 32 : 48) * 16), dim3(256), 0, stream,
                     q, kb, vb, o, opart, stats, mode);
  if (mode == 0)
    hipLaunchKernelGGL(merge_kernel, dim3(2048), dim3(256), 0, stream, opart, stats, o);

  int n4 = nslots * KSR / 4;
  hipLaunchKernelGGL(copy_caches_kernel, dim3(4096), dim3(256), 0, stream,
                     (const f32x4*)kc, (const f32x4*)vc, (f32x4*)okc, (f32x4*)ovc, n4);
  int nthreads = t * (KSR / 4);
  hipLaunchKernelGGL(scatter_kernel, dim3((nthreads + 255) / 256), dim3(256), 0, stream,
                     k, v, slot, okc, ovc, t);
}

// Round 8
// 249.467 us; speedup vs baseline: 1.0843x; 1.0843x over previous
//
#include <hip/hip_runtime.h>
#include <stdint.h>
#include <type_traits>

#define NH 16
#define NKV 4
#define HD 128
#define QS (NH*HD)     /* 2048 */
#define KSR (NKV*HD)   /* 512  */
#define SCALE 0.08838834764831845f
#define LOG2E 1.4426950408889634f
#define CT 32          /* tiles per chunk (split mode) */

typedef float f32x4 __attribute__((ext_vector_type(4)));
typedef float f32x16 __attribute__((ext_vector_type(16)));
typedef __bf16 bf16x8 __attribute__((ext_vector_type(8)));
typedef __bf16 bf16x4 __attribute__((ext_vector_type(4)));
typedef unsigned int u32x4 __attribute__((ext_vector_type(4)));

__device__ __forceinline__ void gll16(const void* g, void* l) {
  __builtin_amdgcn_global_load_lds((const __attribute__((address_space(1))) void*)g,
                                   (__attribute__((address_space(3))) void*)l, 16, 0, 0);
}

__device__ __forceinline__ unsigned cvt_pk_bf16(float a, float b) {
  unsigned r;
  asm("v_cvt_pk_bf16_f32 %0, %1, %2" : "=v"(r) : "v"(a), "v"(b));
  return r;  // lo16 = bf16(a), hi16 = bf16(b)
}

// ---------------------------------------------------------------------------
// Prepass: K -> bf16 * (SCALE*log2e), swizzled image [tile][row][col^swz];
//          V -> bf16 transposed image [tile][d][key^swz].
// ---------------------------------------------------------------------------
__global__ __launch_bounds__(256) void prepass_kernel(
    const float* __restrict__ k, const float* __restrict__ v,
    __bf16* __restrict__ kb, __bf16* __restrict__ vb) {
  const int tid = threadIdx.x;
  const int kvh = blockIdx.x >> 6;
  const int kt = blockIdx.x & 63;
  const size_t ibase = (size_t)(kvh * 64 + kt) << 13;
  const float KS = SCALE * LOG2E;
#pragma unroll
  for (int rep = 0; rep < 4; ++rep) {
    int i = tid + rep * 256;
    int row = i >> 4, c8 = (i & 15) << 3;
    const float* src = k + (size_t)(kt * 64 + row) * KSR + kvh * HD + c8;
    f32x4 a = *(const f32x4*)src, b = *(const f32x4*)(src + 4);
    bf16x8 t;
#pragma unroll
    for (int e = 0; e < 4; ++e) { t[e] = (__bf16)(a[e] * KS); t[4 + e] = (__bf16)(b[e] * KS); }
    *(bf16x8*)&kb[ibase + row * 128 + (c8 ^ ((row & 7) << 3))] = t;
  }
#pragma unroll
  for (int rep = 0; rep < 4; ++rep) {
    int i = tid + rep * 256;
    int d = i >> 3, k8 = (i & 7) << 3;
    bf16x8 t;
#pragma unroll
    for (int w = 0; w < 8; ++w)
      t[w] = (__bf16)v[(size_t)(kt * 64 + k8 + w) * KSR + kvh * HD + d];
    *(bf16x8*)&vb[ibase + d * 64 + (k8 ^ ((d & 7) << 3))] = t;
  }
}

// ---------------------------------------------------------------------------
// Attention: 4 waves x 32 q-rows; KVBLK=64; 32x32x16 MFMA; P in registers
// (cvt_pk + permlane32_swap); K/V via global_load_lds, dbuf, counted vmcnt.
// ---------------------------------------------------------------------------
__global__ __launch_bounds__(256, 2) void attn_kernel(
    const float* __restrict__ q, const __bf16* __restrict__ kb,
    const __bf16* __restrict__ vb, float* __restrict__ o,
    __bf16* __restrict__ opart, float2* __restrict__ stats, int mode) {
  __shared__ __bf16 Kt[2][64][128];
  __shared__ __bf16 VT[2][128][64];

  const int tid = threadIdx.x;
  const int lane = tid & 63;
  const int wid = tid >> 6;
  const int nq = lane & 31, hi = lane >> 5;
  const int h = blockIdx.x & 15;
  const int u = blockIdx.x >> 4;

  int qt, c;
  if (mode) { qt = 31 - u; c = 0; }
  else if (u < 16) { qt = 31 - u; c = 0; }
  else { qt = 47 - u; c = (u < 32) ? 1 : 0; }

  const int kvh = h >> 2;
  const int nch = (!mode && qt >= 16) ? 2 : 1;
  const int t0 = c * CT;
  const int maxt = mode ? 64 : CT;
  int ntb = 2 * qt + 2 - t0;
  if (ntb > maxt) ntb = maxt;
  const int qrow0 = qt * 128 + wid * 32;
  const int limit32 = qt * 4 + wid + 1;
  const int swz = (nq & 7) << 3;

  // ---- Q fragments (B-operand): lane holds Q[qrow0+nq][ks*16 + hi*8 + e] ----
  bf16x8 qf[8];
  {
    const float* qp = q + (size_t)(qrow0 + nq) * QS + h * HD + hi * 8;
#pragma unroll
    for (int ks = 0; ks < 8; ++ks) {
      f32x4 a = *(const f32x4*)(qp + ks * 16);
      f32x4 b = *(const f32x4*)(qp + ks * 16 + 4);
      bf16x8 t;
#pragma unroll
      for (int e = 0; e < 4; ++e) { t[e] = (__bf16)a[e]; t[4 + e] = (__bf16)b[e]; }
      qf[ks] = t;
    }
  }

  f32x16 oacc[4];
#pragma unroll
  for (int vt = 0; vt < 4; ++vt)
#pragma unroll
    for (int e = 0; e < 16; ++e) oacc[vt][e] = 0.f;
  float mrun = -1e30f, lrun = 0.f;

  auto stageKV = [&](int ktg, int buf) {
    const size_t gb = ((size_t)(kvh * 64 + ktg)) << 13;
    const __bf16* gK = kb + gb + tid * 8;
    const __bf16* gV = vb + gb + tid * 8;
    __bf16* lK = &Kt[buf][0][0] + tid * 8;
    __bf16* lV = &VT[buf][0][0] + tid * 8;
#pragma unroll
    for (int i = 0; i < 4; ++i) gll16(gK + i * 2048, lK + i * 2048);
#pragma unroll
    for (int i = 0; i < 4; ++i) gll16(gV + i * 2048, lV + i * 2048);
  };

  auto tile = [&](auto NGC, int buf) {
    constexpr int NG = decltype(NGC)::value;
    f32x16 sacc[NG];
    // ---- QK: S[key][q], q = lane&31, key = (reg&3)+8*(reg>>2)+4*hi + 32*grp ----
#pragma unroll
    for (int grp = 0; grp < NG; ++grp) {
      f32x16 cc;
#pragma unroll
      for (int e = 0; e < 16; ++e) cc[e] = 0.f;
      __builtin_amdgcn_s_setprio(1);
#pragma unroll
      for (int ks = 0; ks < 8; ++ks) {
        bf16x8 kf = *(const bf16x8*)&Kt[buf][grp * 32 + nq][(ks * 16 + hi * 8) ^ swz];
        cc = __builtin_amdgcn_mfma_f32_32x32x16_bf16(kf, qf[ks], cc, 0, 0, 0);
      }
      __builtin_amdgcn_s_setprio(0);
      sacc[grp] = cc;
    }
    // ---- softmax (log2 domain; K pre-scaled by SCALE*log2e) ----
    float mx = sacc[0][0];
#pragma unroll
    for (int grp = 0; grp < NG; ++grp)
#pragma unroll
      for (int e = 0; e < 16; ++e)
        if (grp || e) mx = fmaxf(mx, sacc[grp][e]);
    mx = fmaxf(mx, __shfl_xor(mx, 32));
    float mold = mrun;
    float mnew = fmaxf(mold, mx);
    unsigned long long chg = __ballot(mx > mold);
    mrun = mnew;
    float ts = 0.f;
    unsigned pk[NG * 8];
#pragma unroll
    for (int grp = 0; grp < NG; ++grp)
#pragma unroll
      for (int w = 0; w < 8; ++w) {
        float p0 = exp2f(sacc[grp][2 * w] - mnew);
        float p1 = exp2f(sacc[grp][2 * w + 1] - mnew);
        ts += p0 + p1;
        pk[grp * 8 + w] = cvt_pk_bf16(p0, p1);
      }
    ts += __shfl_xor(ts, 32);
    if (chg) {
      float cf = exp2f(mold - mnew);
      lrun = lrun * cf + ts;
#pragma unroll
      for (int vt = 0; vt < 4; ++vt)
#pragma unroll
        for (int e = 0; e < 16; ++e) oacc[vt][e] *= cf;
    } else {
      lrun += ts;
    }
    // ---- P fragments via permlane32_swap (keys redistributed lo/hi) ----
    bf16x8 paf[NG * 2];
#pragma unroll
    for (int grp = 0; grp < NG; ++grp)
#pragma unroll
      for (int s = 0; s < 2; ++s) {
        unsigned a0 = pk[grp * 8 + 4 * s + 0], a1 = pk[grp * 8 + 4 * s + 2];
        unsigned b0 = pk[grp * 8 + 4 * s + 1], b1 = pk[grp * 8 + 4 * s + 3];
        asm("v_permlane32_swap_b32 %0, %1" : "+v"(a0), "+v"(a1));
        asm("v_permlane32_swap_b32 %0, %1" : "+v"(b0), "+v"(b1));
        u32x4 uu;
        uu[0] = a0; uu[1] = b0; uu[2] = a1; uu[3] = b1;
        paf[grp * 2 + s] = __builtin_bit_cast(bf16x8, uu);
      }
    // ---- PV: O[dim][q] via mfma(V^T, P); q = lane&31 like sacc ----
    __builtin_amdgcn_s_setprio(1);
#pragma unroll
    for (int vt = 0; vt < 4; ++vt)
#pragma unroll
      for (int s = 0; s < NG * 2; ++s) {
        bf16x8 vf = *(const bf16x8*)&VT[buf][vt * 32 + nq][(s * 16 + hi * 8) ^ swz];
        oacc[vt] = __builtin_amdgcn_mfma_f32_32x32x16_bf16(vf, paf[s], oacc[vt], 0, 0, 0);
      }
    __builtin_amdgcn_s_setprio(0);
  };

  // ---- main loop: stage(j+1) in flight across barriers; vmcnt(8) drains KV(j) ----
  stageKV(t0, 0);
  for (int j = 0; j < ntb; ++j) {
    const int buf = j & 1;
    if (j + 1 < ntb) {
      stageKV(t0 + j + 1, buf ^ 1);
      asm volatile("s_waitcnt vmcnt(8)" ::: "memory");
    } else {
      asm volatile("s_waitcnt vmcnt(0)" ::: "memory");
    }
    __builtin_amdgcn_s_barrier();
    const int rem = limit32 - 2 * (t0 + j);
    if (rem >= 2)      tile(std::integral_constant<int, 2>{}, buf);
    else if (rem == 1) tile(std::integral_constant<int, 1>{}, buf);
    __builtin_amdgcn_s_barrier();
  }

  // ---- epilogue: lane q = nq; dim = vt*32 + 8*G + 4*hi + e ----
  if (nch == 1) {
    float inv = 1.0f / lrun;
    float* op = o + (size_t)(qrow0 + nq) * QS + h * HD + 4 * hi;
#pragma unroll
    for (int vt = 0; vt < 4; ++vt)
#pragma unroll
      for (int G = 0; G < 4; ++G) {
        f32x4 t;
#pragma unroll
        for (int e = 0; e < 4; ++e) t[e] = oacc[vt][4 * G + e] * inv;
        *(f32x4*)(op + vt * 32 + 8 * G) = t;
      }
  } else {
    const int slot = (h * 16 + (qt - 16)) * 2 + c;
    const int rl = wid * 32 + nq;
    __bf16* op = opart + (size_t)slot * 16384 + rl * 128 + 4 * hi;
#pragma unroll
    for (int vt = 0; vt < 4; ++vt)
#pragma unroll
      for (int G = 0; G < 4; ++G) {
        bf16x4 t;
#pragma unroll
        for (int e = 0; e < 4; ++e) t[e] = (__bf16)oacc[vt][4 * G + e];
        *(bf16x4*)(op + vt * 32 + 8 * G) = t;
      }
    if (hi == 0) stats[slot * 128 + rl] = make_float2(mrun, lrun);
  }
}

// ---------------------------------------------------------------------------
// Merge two chunk-partials per row (qt >= 16 only); stats are log2-domain.
// ---------------------------------------------------------------------------
__global__ __launch_bounds__(256) void merge_kernel(
    const __bf16* __restrict__ opart, const float2* __restrict__ stats,
    float* __restrict__ o) {
  const int bi = blockIdx.x;
  const int qtr = bi >> 7;
  const int rm = bi & 127;
  const int h = rm >> 3;
  const int rb = rm & 7;
  const int t = threadIdx.x;
  const int rl = rb * 16 + (t >> 4);
  const int d8 = (t & 15) << 3;
  const int slot = (h * 16 + qtr) * 2;
  float2 s0 = stats[slot * 128 + rl];
  float2 s1 = stats[(slot + 1) * 128 + rl];
  float M = fmaxf(s0.x, s1.x);
  float w0 = exp2f(s0.x - M), w1 = exp2f(s1.x - M);
  float inv = 1.0f / (s0.y * w0 + s1.y * w1);
  bf16x8 a = *(const bf16x8*)&opart[(size_t)slot * 16384 + rl * 128 + d8];
  bf16x8 b = *(const bf16x8*)&opart[(size_t)(slot + 1) * 16384 + rl * 128 + d8];
  float* dst = o + (size_t)((16 + qtr) * 128 + rl) * QS + h * HD + d8;
  f32x4 o0, o1;
#pragma unroll
  for (int e = 0; e < 4; ++e) o0[e] = ((float)a[e] * w0 + (float)b[e] * w1) * inv;
#pragma unroll
  for (int e = 0; e < 4; ++e) o1[e] = ((float)a[4 + e] * w0 + (float)b[4 + e] * w1) * inv;
  *(f32x4*)dst = o0;
  *(f32x4*)(dst + 4) = o1;
}

// ---------------------------------------------------------------------------
// Cache copy then scatter
// ---------------------------------------------------------------------------
__global__ void copy_caches_kernel(const f32x4* __restrict__ kc, const f32x4* __restrict__ vc,
                                   f32x4* __restrict__ okc, f32x4* __restrict__ ovc, int n4) {
  int i = blockIdx.x * blockDim.x + threadIdx.x;
  int stride = gridDim.x * blockDim.x;
  for (; i < n4; i += stride) {
    okc[i] = kc[i];
    ovc[i] = vc[i];
  }
}

__global__ void scatter_kernel(const float* __restrict__ k, const float* __restrict__ v,
                               const int* __restrict__ slot, float* __restrict__ okc,
                               float* __restrict__ ovc, int t) {
  int i = blockIdx.x * blockDim.x + threadIdx.x;
  int row = i >> 7, c = i & 127;
  if (row < t) {
    int s = slot[row];
    ((f32x4*)okc)[(size_t)s * 128 + c] = ((const f32x4*)k)[(size_t)row * 128 + c];
    ((f32x4*)ovc)[(size_t)s * 128 + c] = ((const f32x4*)v)[(size_t)row * 128 + c];
  }
}

extern "C" void kernel_launch(void* const* d_in, const int* in_sizes, int n_in,
                              void* d_out, int out_size, void* d_ws, size_t ws_size,
                              hipStream_t stream) {
  const float* q = (const float*)d_in[0];
  const float* k = (const float*)d_in[1];
  const float* v = (const float*)d_in[2];
  const float* kc = (const float*)d_in[3];
  const float* vc = (const float*)d_in[4];
  const int* slot = (const int*)d_in[5];

  const int t = in_sizes[0] / QS;        // 4096
  const int nslots = in_sizes[3] / KSR;  // 8192

  float* o = (float*)d_out;
  float* okc = o + (size_t)t * QS;
  float* ovc = okc + (size_t)nslots * KSR;

  __bf16* kb = (__bf16*)d_ws;
  __bf16* vb = kb + 2097152;
  const size_t off_op = (size_t)8 << 20;
  const size_t off_st = off_op + (size_t)512 * 16384 * 2;
  const size_t need_split = off_st + (size_t)512 * 128 * 8;
  __bf16* opart = (__bf16*)((char*)d_ws + off_op);
  float2* stats = (float2*)((char*)d_ws + off_st);

  const int mode = (ws_size >= need_split) ? 0 : 1;

  hipLaunchKernelGGL(prepass_kernel, dim3(256), dim3(256), 0, stream, k, v, kb, vb);
  hipLaunchKernelGGL(attn_kernel, dim3((mode ? 32 : 48) * 16), dim3(256), 0, stream,
                     q, kb, vb, o, opart, stats, mode);
  if (mode == 0)
    hipLaunchKernelGGL(merge_kernel, dim3(2048), dim3(256), 0, stream, opart, stats, o);

  int n4 = nslots * KSR / 4;
  hipLaunchKernelGGL(copy_caches_kernel, dim3(4096), dim3(256), 0, stream,
                     (const f32x4*)kc, (const f32x4*)vc, (f32x4*)okc, (f32x4*)ovc, n4);
  int nthreads = t * (KSR / 4);
  hipLaunchKernelGGL(scatter_kernel, dim3((nthreads + 255) / 256), dim3(256), 0, stream,
                     k, v, slot, okc, ovc, t);
}